// Round 11
// baseline (159.089 us; speedup 1.0000x reference)
//
#include <hip/hip_runtime.h>
#include <math.h>

typedef __attribute__((ext_vector_type(8))) short bf16x8;
typedef __attribute__((ext_vector_type(4))) float f32x4;
typedef unsigned short u16;
typedef unsigned int u32;

#define BSZ   8192
#define BN_EPS 1e-5f

// ---------- helpers ----------
__device__ inline u16 f2bf(float x) {            // RNE fp32 -> bf16
    u32 u = __float_as_uint(x);
    u32 r = (u + 0x7FFFu + ((u >> 16) & 1u)) >> 16;
    return (u16)r;
}
__device__ inline float bf2f_lo(u32 p) { return __uint_as_float(p << 16); }
__device__ inline float bf2f_hi(u32 p) { return __uint_as_float(p & 0xFFFF0000u); }

__device__ inline void async_g2l(const void* g, void* l) {
    __builtin_amdgcn_global_load_lds(
        (const __attribute__((address_space(1))) void*)g,
        (__attribute__((address_space(3))) void*)l, 16, 0, 0);
}

// ---------- Wvo = out_w @ Wv, bvo = out_w @ bv + out_b (fp32, tiny) ----------
__global__ __launch_bounds__(256)
void wvo_kernel(const float* __restrict__ in_w, const float* __restrict__ in_b,
                const float* __restrict__ out_w, const float* __restrict__ out_b,
                float* __restrict__ wvo, float* __restrict__ bvo)
{
    const int i = blockIdx.x;
    const int j = threadIdx.x;
    const float* Wv = in_w + 512 * 256;
    float s = 0.f;
#pragma unroll 8
    for (int k = 0; k < 256; ++k)
        s = fmaf(out_w[i * 256 + k], Wv[k * 256 + j], s);
    wvo[i * 256 + j] = s;
    if (i == 0) {
        const float* bv = in_b + 512;
        float t = 0.f;
        for (int k = 0; k < 256; ++k)
            t = fmaf(out_w[j * 256 + k], bv[k], t);
        bvo[j] = t + out_b[j];
    }
}

// ---------- convert all weight matrices to bf16 (packed buffer) ----------
// elem offsets (u16): wvo 0, Wc 65536, Wb 589824, Wf 1114112, Wt 1245184,
//                     Wg1 1441792, W1 1507328   (total 1769472)
__global__ __launch_bounds__(256)
void cvt_weights(const float* __restrict__ wvo, const float* __restrict__ Wc,
                 const float* __restrict__ Wb,  const float* __restrict__ Wf,
                 const float* __restrict__ Wt,  const float* __restrict__ Wg1,
                 const float* __restrict__ W1f, u16* __restrict__ dst)
{
    int gid = blockIdx.x * 256 + threadIdx.x;    // unit = 8 floats
    const float* src; u16* d; int loc;
    if      (gid <   8192) { src = wvo; d = dst + 0;       loc = gid; }
    else if (gid <  73728) { src = Wc;  d = dst + 65536;   loc = gid - 8192; }
    else if (gid < 139264) { src = Wb;  d = dst + 589824;  loc = gid - 73728; }
    else if (gid < 155648) { src = Wf;  d = dst + 1114112; loc = gid - 139264; }
    else if (gid < 180224) { src = Wt;  d = dst + 1245184; loc = gid - 155648; }
    else if (gid < 188416) { src = Wg1; d = dst + 1441792; loc = gid - 180224; }
    else                   { src = W1f; d = dst + 1507328; loc = gid - 188416; }
    const float4 v0 = *(const float4*)(src + (size_t)loc * 8);
    const float4 v1 = *(const float4*)(src + (size_t)loc * 8 + 4);
    uint4 o;
    o.x = (u32)f2bf(v0.x) | ((u32)f2bf(v0.y) << 16);
    o.y = (u32)f2bf(v0.z) | ((u32)f2bf(v0.w) << 16);
    o.z = (u32)f2bf(v1.x) | ((u32)f2bf(v1.y) << 16);
    o.w = (u32)f2bf(v1.z) | ((u32)f2bf(v1.w) << 16);
    *(uint4*)(d + (size_t)loc * 8) = o;
}

// ---------- projection GEMM (R6/R10 structure, verified best: ~83us) ----------
__global__ __launch_bounds__(256)
void gemm_proj(const float* __restrict__ A0, const float* __restrict__ A1,
               const float* __restrict__ A2, const float* __restrict__ A3,
               const u16* __restrict__ Wp0, const u16* __restrict__ Wp1,
               const u16* __restrict__ Wp2, const u16* __restrict__ Wp3,
               const float* __restrict__ b0, const float* __restrict__ b1,
               const float* __restrict__ b2, const float* __restrict__ b3,
               u16* __restrict__ fb)
{
    __shared__ u16 As[2][4096];
    __shared__ u16 Bs[2][16384];
    const int m = blockIdx.y;
    const float* A  = (m == 0) ? A0 : (m == 1) ? A1 : (m == 2) ? A2 : A3;
    const u16* Wp   = (m == 0) ? Wp0 : (m == 1) ? Wp1 : (m == 2) ? Wp2 : Wp3;
    const float* bi = (m == 0) ? b0 : (m == 1) ? b1 : (m == 2) ? b2 : b3;
    const int K     = (m == 0) ? 2048 : (m == 1) ? 2048 : (m == 2) ? 512 : 768;
    const int nt = K >> 6;

    const int t = threadIdx.x;
    const int w = t >> 6, l = t & 63;
    const int bm = blockIdx.x * 64;
    const int arow = t >> 2, akq = t & 3;

    float4 rA[4], rB[4];
    auto loadA = [&](int k0, float4* r) {
        const float* g = A + (size_t)(bm + arow) * K + k0 + akq * 16;
#pragma unroll
        for (int q = 0; q < 4; ++q) r[q] = *(const float4*)(g + q * 4);
    };
    auto writeA = [&](int buf, const float4* r) {
        bf16x8 p0, p1;
        p0[0] = (short)f2bf(r[0].x); p0[1] = (short)f2bf(r[0].y);
        p0[2] = (short)f2bf(r[0].z); p0[3] = (short)f2bf(r[0].w);
        p0[4] = (short)f2bf(r[1].x); p0[5] = (short)f2bf(r[1].y);
        p0[6] = (short)f2bf(r[1].z); p0[7] = (short)f2bf(r[1].w);
        p1[0] = (short)f2bf(r[2].x); p1[1] = (short)f2bf(r[2].y);
        p1[2] = (short)f2bf(r[2].z); p1[3] = (short)f2bf(r[2].w);
        p1[4] = (short)f2bf(r[3].x); p1[5] = (short)f2bf(r[3].y);
        p1[6] = (short)f2bf(r[3].z); p1[7] = (short)f2bf(r[3].w);
        char* abw = (char*)As[buf];
        *(bf16x8*)(abw + arow * 128 + (((akq * 2 + 0) ^ (arow & 7)) << 4)) = p0;
        *(bf16x8*)(abw + arow * 128 + (((akq * 2 + 1) ^ (arow & 7)) << 4)) = p1;
    };
    auto issueB = [&](int k0, int buf) {
#pragma unroll
        for (int it = 0; it < 8; ++it) {
            const int n  = it * 32 + w * 8 + (l >> 3);
            const int ch = (l & 7) ^ (n & 7);
            async_g2l(Wp + (size_t)n * K + k0 + ch * 8, Bs[buf] + it * 2048 + w * 512);
        }
    };

    f32x4 acc[4][4];
    const f32x4 z = {0.f, 0.f, 0.f, 0.f};
#pragma unroll
    for (int i = 0; i < 4; ++i)
#pragma unroll
        for (int j = 0; j < 4; ++j) acc[i][j] = z;

    auto compute = [&](const char* abr, const char* bbr) {
#pragma unroll
        for (int kk = 0; kk < 2; ++kk) {
            bf16x8 af[4], bq[4];
            const int ch = kk * 4 + (l >> 4);
#pragma unroll
            for (int i = 0; i < 4; ++i) {
                const int fr = i * 16 + (l & 15);
                af[i] = *(const bf16x8*)(abr + fr * 128 + ((ch ^ (fr & 7)) << 4));
            }
#pragma unroll
            for (int j = 0; j < 4; ++j) {
                const int n = w * 64 + j * 16 + (l & 15);
                bq[j] = *(const bf16x8*)(bbr + n * 128 + ((ch ^ (n & 7)) << 4));
            }
#pragma unroll
            for (int i = 0; i < 4; ++i)
#pragma unroll
                for (int j = 0; j < 4; ++j)
                    acc[i][j] = __builtin_amdgcn_mfma_f32_16x16x32_bf16(
                        af[i], bq[j], acc[i][j], 0, 0, 0);
        }
    };

    loadA(0, rA);
    writeA(0, rA);
    issueB(0, 0);
    loadA(64, rB);
    issueB(64, 1);
    loadA(128, rA);
    asm volatile("s_waitcnt vmcnt(16) lgkmcnt(0)" ::: "memory");
    __builtin_amdgcn_sched_barrier(0);
    __builtin_amdgcn_s_barrier();

    for (int t0 = 0; t0 < nt; t0 += 2) {
        compute((const char*)As[0], (const char*)Bs[0]);
        writeA(1, rB);
        __builtin_amdgcn_s_barrier();
        if (t0 + 3 < nt) {
            loadA((t0 + 3) * 64, rB);
            issueB((t0 + 2) * 64, 0);
            asm volatile("s_waitcnt vmcnt(12) lgkmcnt(0)" ::: "memory");
        } else if (t0 + 2 < nt) {
            issueB((t0 + 2) * 64, 0);
            asm volatile("s_waitcnt vmcnt(8) lgkmcnt(0)" ::: "memory");
        } else {
            asm volatile("s_waitcnt vmcnt(0) lgkmcnt(0)" ::: "memory");
        }
        __builtin_amdgcn_sched_barrier(0);
        __builtin_amdgcn_s_barrier();

        compute((const char*)As[1], (const char*)Bs[1]);
        if (t0 + 2 < nt) writeA(0, rA);
        __builtin_amdgcn_s_barrier();
        if (t0 + 4 < nt) {
            loadA((t0 + 4) * 64, rA);
            issueB((t0 + 3) * 64, 1);
            asm volatile("s_waitcnt vmcnt(12) lgkmcnt(0)" ::: "memory");
        } else if (t0 + 3 < nt) {
            issueB((t0 + 3) * 64, 1);
            asm volatile("s_waitcnt vmcnt(8) lgkmcnt(0)" ::: "memory");
        } else {
            asm volatile("s_waitcnt vmcnt(0) lgkmcnt(0)" ::: "memory");
        }
        __builtin_amdgcn_sched_barrier(0);
        __builtin_amdgcn_s_barrier();
    }

#pragma unroll
    for (int j = 0; j < 4; ++j) {
        const int col = w * 64 + j * 16 + (l & 15);
        const float bv = bi[col];
#pragma unroll
        for (int i = 0; i < 4; ++i)
#pragma unroll
            for (int r = 0; r < 4; ++r) {
                const int rt = i * 16 + ((l >> 4) << 2) + r;
                fb[((size_t)(bm + rt) * 4 + m) * 256 + col] = f2bf(acc[i][j][r] + bv);
            }
    }
}

// ---------- fused so+gate+combined+W1(+BN partials): BM=32 f-rows ----------
// Stages: f->so (8 it), so->gate (8 it), combined in-place in LDS,
//         h = comb @ W1^T + b1 (32 it, comb read from LDS; M=8 valid h-rows),
//         epilogue: h + per-block BN column partials.
__global__ __launch_bounds__(256)
void fused_sgw1(const u16* __restrict__ fb, const u16* __restrict__ wvo_bf,
                const float* __restrict__ bvo,
                const u16* __restrict__ wg1_bf, const float* __restrict__ bg1,
                const float* __restrict__ wg2, const float* __restrict__ bg2,
                const u16* __restrict__ w1p, const float* __restrict__ b1p,
                float* __restrict__ h, float* __restrict__ psum,
                float* __restrict__ psq)
{
    __shared__ u16 FS[8192];        // 16KB: [32 rows][256], XOR-swizzled chunks
    __shared__ u16 Bs[2][8192];     // 16KB x2 weight staging
    __shared__ float gp[4][32];
    __shared__ float gate_s[32];
    const int t = threadIdx.x, w = t >> 6, l = t & 63;
    const int bm = blockIdx.x * 32;
    char* const fs = (char*)FS;

    // stage f tile: linear LDS dest, pre-swizzled global source
#pragma unroll
    for (int it = 0; it < 4; ++it) {
        const int r0 = (w * 4 + it) * 2;
        const int row = r0 + (l >> 5);
        const int ch = (l & 31) ^ (row & 7);
        async_g2l(fb + (size_t)(bm + row) * 256 + ch * 8, FS + r0 * 256);
    }
    auto issueB256 = [&](const u16* Wp, int k0, int buf) {
#pragma unroll
        for (int it = 0; it < 4; ++it) {
            const int n0 = (w * 4 + it) * 16;
            async_g2l(Wp + (size_t)(n0 + (l >> 2)) * 256 + k0 + (l & 3) * 8,
                      Bs[buf] + n0 * 32);
        }
    };
    auto issueB1024 = [&](int k0, int buf) {       // W1 staging, K=1024
#pragma unroll
        for (int it = 0; it < 4; ++it) {
            const int n0 = (w * 4 + it) * 16;
            async_g2l(w1p + (size_t)(n0 + (l >> 2)) * 1024 + k0 + (l & 3) * 8,
                      Bs[buf] + n0 * 32);
        }
    };
    issueB256(wvo_bf, 0, 0);
    __syncthreads();

    const f32x4 z = {0.f, 0.f, 0.f, 0.f};

    // ---- stage 1: so = f @ Wvo^T ----
    f32x4 acc[2][4];
#pragma unroll
    for (int i = 0; i < 2; ++i)
#pragma unroll
        for (int j = 0; j < 4; ++j) acc[i][j] = z;

    for (int ks = 0; ks < 8; ++ks) {
        const int cur = ks & 1;
        if (ks < 7) issueB256(wvo_bf, (ks + 1) * 32, cur ^ 1);
        else        issueB256(wg1_bf, 0, 0);
        bf16x8 af[2], bq[4];
#pragma unroll
        for (int i = 0; i < 2; ++i) {
            const int row = i * 16 + (l & 15);
            af[i] = *(const bf16x8*)(fs + row * 512 +
                      (((ks * 4 + (l >> 4)) ^ (row & 7)) << 4));
        }
#pragma unroll
        for (int j = 0; j < 4; ++j)
            bq[j] = *(const bf16x8*)((char*)Bs[cur] +
                      (w * 64 + j * 16 + (l & 15)) * 64 + (l >> 4) * 16);
#pragma unroll
        for (int i = 0; i < 2; ++i)
#pragma unroll
            for (int j = 0; j < 4; ++j)
                acc[i][j] = __builtin_amdgcn_mfma_f32_16x16x32_bf16(
                    af[i], bq[j], acc[i][j], 0, 0, 0);
        __syncthreads();
    }

    // write so (bf16, +bvo) back into FS (f is dead)
#pragma unroll
    for (int j = 0; j < 4; ++j) {
        const int col = w * 64 + j * 16 + (l & 15);
        const float bv = bvo[col];
#pragma unroll
        for (int i = 0; i < 2; ++i)
#pragma unroll
            for (int r = 0; r < 4; ++r) {
                const int rt = i * 16 + ((l >> 4) << 2) + r;
                *(u16*)(fs + rt * 512 + (((col >> 3) ^ (rt & 7)) << 4) + (col & 7) * 2)
                    = f2bf(acc[i][j][r] + bv);
            }
    }
    __syncthreads();

    // ---- stage 2: gate GEMM ----
    f32x4 g2[2][4];
#pragma unroll
    for (int i = 0; i < 2; ++i)
#pragma unroll
        for (int j = 0; j < 4; ++j) g2[i][j] = z;

    for (int ks = 0; ks < 8; ++ks) {
        const int cur = ks & 1;
        if (ks < 7) issueB256(wg1_bf, (ks + 1) * 32, cur ^ 1);
        else        issueB1024(0, 0);              // prefetch W1 k0 into Bs[0]
        bf16x8 af[2], bq[4];
#pragma unroll
        for (int i = 0; i < 2; ++i) {
            const int row = i * 16 + (l & 15);
            af[i] = *(const bf16x8*)(fs + row * 512 +
                      (((ks * 4 + (l >> 4)) ^ (row & 7)) << 4));
        }
#pragma unroll
        for (int j = 0; j < 4; ++j)
            bq[j] = *(const bf16x8*)((char*)Bs[cur] +
                      (w * 64 + j * 16 + (l & 15)) * 64 + (l >> 4) * 16);
#pragma unroll
        for (int i = 0; i < 2; ++i)
#pragma unroll
            for (int j = 0; j < 4; ++j)
                g2[i][j] = __builtin_amdgcn_mfma_f32_16x16x32_bf16(
                    af[i], bq[j], g2[i][j], 0, 0, 0);
        __syncthreads();
    }

    // gate reduce
    {
        float s[2][4];
#pragma unroll
        for (int i = 0; i < 2; ++i)
#pragma unroll
            for (int r = 0; r < 4; ++r) s[i][r] = 0.f;
#pragma unroll
        for (int j = 0; j < 4; ++j) {
            const int col = w * 64 + j * 16 + (l & 15);
            const float bv = bg1[col], wv = wg2[col];
#pragma unroll
            for (int i = 0; i < 2; ++i)
#pragma unroll
                for (int r = 0; r < 4; ++r)
                    s[i][r] += fmaxf(g2[i][j][r] + bv, 0.f) * wv;
        }
#pragma unroll
        for (int off = 1; off < 16; off <<= 1)
#pragma unroll
            for (int i = 0; i < 2; ++i)
#pragma unroll
                for (int r = 0; r < 4; ++r)
                    s[i][r] += __shfl_xor(s[i][r], off);
        if ((l & 15) == 0) {
#pragma unroll
            for (int i = 0; i < 2; ++i)
#pragma unroll
                for (int r = 0; r < 4; ++r)
                    gp[w][i * 16 + ((l >> 4) << 2) + r] = s[i][r];
        }
    }
    __syncthreads();
    if (t < 32) {
        const float g = gp[0][t] + gp[1][t] + gp[2][t] + gp[3][t] + bg2[0];
        gate_s[t] = 1.f / (1.f + expf(-g));
    }
    __syncthreads();

    // ---- stage 3: combined, IN-PLACE in FS (same layout/swizzle) ----
    {
        const int p2 = t & 127;
        const int gh = t >> 7;
#pragma unroll
        for (int gg = 0; gg < 4; ++gg) {
            const int g = gh * 4 + gg;
            const int d0 = p2 * 2;
            float lo4[4], hi4[4], gv[4];
#pragma unroll
            for (int mm = 0; mm < 4; ++mm) {
                const int row = g * 4 + mm;
                const u32 v = *(const u32*)(fs + row * 512 +
                                (((d0 >> 3) ^ (row & 7)) << 4) + (d0 & 7) * 2);
                lo4[mm] = bf2f_lo(v); hi4[mm] = bf2f_hi(v);
                gv[mm] = gate_s[g * 4 + mm];
            }
            const float cl = 0.25f * (lo4[0] + lo4[1] + lo4[2] + lo4[3]);
            const float ch = 0.25f * (hi4[0] + hi4[1] + hi4[2] + hi4[3]);
#pragma unroll
            for (int mm = 0; mm < 4; ++mm) {
                const int row = g * 4 + mm;
                const float ol = gv[mm] * lo4[mm] + (1.f - gv[mm]) * cl;
                const float oh = gv[mm] * hi4[mm] + (1.f - gv[mm]) * ch;
                *(u32*)(fs + row * 512 + (((d0 >> 3) ^ (row & 7)) << 4) + (d0 & 7) * 2)
                    = (u32)f2bf(ol) | ((u32)f2bf(oh) << 16);
            }
        }
    }
    __syncthreads();

    // ---- stage 4: h = comb @ W1^T + b1 (comb from LDS; valid h-rows 0..7) ----
    // comb_view[hr][k] = FS[(hr&7)*4 + (k>>8)][k&255]
    f32x4 a4[4];
#pragma unroll
    for (int j = 0; j < 4; ++j) a4[j] = z;

    for (int t0 = 0; t0 < 32; ++t0) {
        const int cur = t0 & 1;
        if (t0 + 1 < 32) issueB1024((t0 + 1) * 32, cur ^ 1);
        const int frow = (l & 7) * 4 + (t0 >> 3);
        const int chnk = (t0 & 7) * 4 + (l >> 4);
        const bf16x8 af = *(const bf16x8*)(fs + frow * 512 +
                            ((chnk ^ (frow & 7)) << 4));
        const char* bb = (const char*)Bs[cur];
#pragma unroll
        for (int j = 0; j < 4; ++j) {
            const bf16x8 bq = *(const bf16x8*)(bb +
                                (w * 64 + j * 16 + (l & 15)) * 64 + (l >> 4) * 16);
            a4[j] = __builtin_amdgcn_mfma_f32_16x16x32_bf16(af, bq, a4[j], 0, 0, 0);
        }
        __syncthreads();
    }

    // ---- epilogue: h + BN column partials ----
    const int hb = blockIdx.x * 8;
#pragma unroll
    for (int j = 0; j < 4; ++j) {
        const int col = w * 64 + j * 16 + (l & 15);
        const float bv = b1p[col];
        float cs = 0.f, cq = 0.f;
        if (l < 32) {
#pragma unroll
            for (int r = 0; r < 4; ++r) {
                const int rt = ((l >> 4) << 2) + r;     // 0..7 valid
                const float v = a4[j][r] + bv;
                h[(size_t)(hb + rt) * 256 + col] = v;
                cs += v;
                cq = fmaf(v, v, cq);
            }
        }
        cs += __shfl_xor(cs, 16); cq += __shfl_xor(cq, 16);
        cs += __shfl_xor(cs, 32); cq += __shfl_xor(cq, 32);
        if ((l >> 4) == 0) {
            psum[(size_t)blockIdx.x * 256 + col] = cs;
            psq[(size_t)blockIdx.x * 256 + col]  = cq;
        }
    }
}

// ---------- BN finalize: one block per feature column, 1024 stripes ----------
__global__ __launch_bounds__(256)
void bn_fin(const float* __restrict__ psum, const float* __restrict__ psq,
            const float* __restrict__ gamma, const float* __restrict__ beta,
            float* __restrict__ scale, float* __restrict__ shift)
{
    __shared__ float ss[4], qq[4];
    const int d = blockIdx.x;
    const int t = threadIdx.x;
    float s = 0.f, q = 0.f;
#pragma unroll
    for (int u = 0; u < 4; ++u) {
        const int p = u * 256 + t;
        s += psum[(size_t)p * 256 + d];
        q += psq[(size_t)p * 256 + d];
    }
#pragma unroll
    for (int off = 1; off < 64; off <<= 1) {
        s += __shfl_xor(s, off);
        q += __shfl_xor(q, off);
    }
    if ((t & 63) == 0) { ss[t >> 6] = s; qq[t >> 6] = q; }
    __syncthreads();
    if (t == 0) {
        s = ss[0] + ss[1] + ss[2] + ss[3];
        q = qq[0] + qq[1] + qq[2] + qq[3];
        const float mu  = s * (1.f / BSZ);
        const float var = q * (1.f / BSZ) - mu * mu;
        const float inv = rsqrtf(var + BN_EPS);
        const float sc  = gamma[d] * inv;
        scale[d] = sc;
        shift[d] = beta[d] - mu * sc;
    }
}

// ---------- final: out = relu(h*scale+shift) @ W2^T + b2 ----------
__global__ __launch_bounds__(256)
void final_kernel(const float* __restrict__ h, const float* __restrict__ scale,
                  const float* __restrict__ shift, const float* __restrict__ W2,
                  const float* __restrict__ b2, float* __restrict__ out)
{
    __shared__ float W2s[26][260];
    __shared__ float scs[256], shs[256];
    const int t = threadIdx.x;
    for (int u = t; u < 26 * 256; u += 256) {
        const int c = u >> 8, n = u & 255;
        W2s[c][(n >> 6) * 65 + (n & 63)] = W2[u];
    }
    scs[t] = scale[t];
    shs[t] = shift[t];
    __syncthreads();

    const int r = blockIdx.x * 64 + (t >> 2);
    const int p = t & 3;
    float acc[26];
#pragma unroll
    for (int c = 0; c < 26; ++c) acc[c] = 0.f;
    const float* hr = h + (size_t)r * 256 + p * 64;
#pragma unroll
    for (int i4 = 0; i4 < 16; ++i4) {
        const float4 v4 = *(const float4*)(hr + i4 * 4);
#pragma unroll
        for (int q = 0; q < 4; ++q) {
            const int i = i4 * 4 + q;
            const int n = p * 64 + i;
            const float vv = (q == 0) ? v4.x : (q == 1) ? v4.y : (q == 2) ? v4.z : v4.w;
            const float v = fmaxf(fmaf(vv, scs[n], shs[n]), 0.f);
            const int sw = p * 65 + i;
#pragma unroll
            for (int c = 0; c < 26; ++c)
                acc[c] = fmaf(v, W2s[c][sw], acc[c]);
        }
    }
#pragma unroll
    for (int off = 1; off < 4; off <<= 1)
#pragma unroll
        for (int c = 0; c < 26; ++c)
            acc[c] += __shfl_xor(acc[c], off);
    if (p == 0) {
#pragma unroll
        for (int c = 0; c < 26; ++c)
            out[(size_t)r * 26 + c] = acc[c] + b2[c];
    }
}

// ---------- launch ----------
extern "C" void kernel_launch(void* const* d_in, const int* in_sizes, int n_in,
                              void* d_out, int out_size, void* d_ws, size_t ws_size,
                              hipStream_t stream)
{
    const float* x_ctx  = (const float*)d_in[0];
    const float* x_body = (const float*)d_in[1];
    const float* x_face = (const float*)d_in[2];
    const float* x_text = (const float*)d_in[3];
    const float* Wc = (const float*)d_in[4];  const float* bc = (const float*)d_in[5];
    const float* Wb = (const float*)d_in[6];  const float* bb = (const float*)d_in[7];
    const float* Wf = (const float*)d_in[8];  const float* bf = (const float*)d_in[9];
    const float* Wt = (const float*)d_in[10]; const float* bt = (const float*)d_in[11];
    const float* in_w  = (const float*)d_in[12]; const float* in_b  = (const float*)d_in[13];
    const float* out_w = (const float*)d_in[14]; const float* out_b = (const float*)d_in[15];
    const float* Wg1 = (const float*)d_in[16]; const float* bg1 = (const float*)d_in[17];
    const float* Wg2 = (const float*)d_in[18]; const float* bg2 = (const float*)d_in[19];
    const float* W1  = (const float*)d_in[20]; const float* b1  = (const float*)d_in[21];
    const float* gamma = (const float*)d_in[22]; const float* beta = (const float*)d_in[23];
    const float* W2  = (const float*)d_in[24]; const float* b2  = (const float*)d_in[25];

    char* wsb = (char*)d_ws;
    u16*   f_bf  = (u16*)(wsb + 0);                    // 16 MB  [32768][256]
    float* h     = (float*)(wsb + (16u << 20));        //  8 MB  [8192][256]
    u16*   wpb   = (u16*)(wsb + (32u << 20));          // 3.54 MB packed bf16 weights
    float* wvo   = (float*)(wsb + (36u << 20));        // 256 KB
    float* bvo   = (float*)(wsb + (36u << 20) + 262144);
    float* psum  = (float*)(wsb + (37u << 20));        // 1 MB [1024][256]
    float* psq   = (float*)(wsb + (38u << 20));        // 1 MB
    float* scale = (float*)(wsb + (39u << 20));
    float* shift = (float*)(wsb + (39u << 20) + 4096);

    u16* wvo_bf = wpb + 0;
    u16* wc_bf  = wpb + 65536;
    u16* wb_bf  = wpb + 589824;
    u16* wf_bf  = wpb + 1114112;
    u16* wt_bf  = wpb + 1245184;
    u16* wg1_bf = wpb + 1441792;
    u16* w1_bf  = wpb + 1507328;

    wvo_kernel<<<256, 256, 0, stream>>>(in_w, in_b, out_w, out_b, wvo, bvo);
    cvt_weights<<<864, 256, 0, stream>>>(wvo, Wc, Wb, Wf, Wt, Wg1, W1, wpb);

    // modality projections -> f_bf [32768][256] (row = b*4+m)
    gemm_proj<<<dim3(128, 4), 256, 0, stream>>>(x_ctx, x_body, x_face, x_text,
                                                wc_bf, wb_bf, wf_bf, wt_bf,
                                                bc, bb, bf, bt, f_bf);

    // so + gate + combined + W1 + BN partials, all fused; 1024 blocks
    fused_sgw1<<<1024, 256, 0, stream>>>(f_bf, wvo_bf, bvo, wg1_bf, bg1,
                                         Wg2, bg2, w1_bf, b1, h, psum, psq);

    bn_fin<<<256, 256, 0, stream>>>(psum, psq, gamma, beta, scale, shift);
    final_kernel<<<128, 256, 0, stream>>>(h, scale, shift, W2, b2, (float*)d_out);
}

// Round 12
// 141.714 us; speedup vs baseline: 1.1226x; 1.1226x over previous
//
#include <hip/hip_runtime.h>
#include <math.h>

typedef __attribute__((ext_vector_type(8))) short bf16x8;
typedef __attribute__((ext_vector_type(4))) float f32x4;
typedef unsigned short u16;
typedef unsigned int u32;

#define BSZ   8192
#define BN_EPS 1e-5f

// ---------- helpers ----------
__device__ inline u16 f2bf(float x) {            // RNE fp32 -> bf16
    u32 u = __float_as_uint(x);
    u32 r = (u + 0x7FFFu + ((u >> 16) & 1u)) >> 16;
    return (u16)r;
}
__device__ inline float bf2f_lo(u32 p) { return __uint_as_float(p << 16); }
__device__ inline float bf2f_hi(u32 p) { return __uint_as_float(p & 0xFFFF0000u); }

__device__ inline void async_g2l(const void* g, void* l) {
    __builtin_amdgcn_global_load_lds(
        (const __attribute__((address_space(1))) void*)g,
        (__attribute__((address_space(3))) void*)l, 16, 0, 0);
}

// ---------- Wvo = out_w @ Wv, bvo = out_w @ bv + out_b (fp32, tiny) ----------
__global__ __launch_bounds__(256)
void wvo_kernel(const float* __restrict__ in_w, const float* __restrict__ in_b,
                const float* __restrict__ out_w, const float* __restrict__ out_b,
                float* __restrict__ wvo, float* __restrict__ bvo)
{
    const int i = blockIdx.x;
    const int j = threadIdx.x;
    const float* Wv = in_w + 512 * 256;
    float s = 0.f;
#pragma unroll 8
    for (int k = 0; k < 256; ++k)
        s = fmaf(out_w[i * 256 + k], Wv[k * 256 + j], s);
    wvo[i * 256 + j] = s;
    if (i == 0) {
        const float* bv = in_b + 512;
        float t = 0.f;
        for (int k = 0; k < 256; ++k)
            t = fmaf(out_w[j * 256 + k], bv[k], t);
        bvo[j] = t + out_b[j];
    }
}

// ---------- convert all weight matrices to bf16 (packed buffer) ----------
// elem offsets (u16): wvo 0, Wc 65536, Wb 589824, Wf 1114112, Wt 1245184,
//                     Wg1 1441792, W1 1507328   (total 1769472)
__global__ __launch_bounds__(256)
void cvt_weights(const float* __restrict__ wvo, const float* __restrict__ Wc,
                 const float* __restrict__ Wb,  const float* __restrict__ Wf,
                 const float* __restrict__ Wt,  const float* __restrict__ Wg1,
                 const float* __restrict__ W1f, u16* __restrict__ dst)
{
    int gid = blockIdx.x * 256 + threadIdx.x;    // unit = 8 floats
    const float* src; u16* d; int loc;
    if      (gid <   8192) { src = wvo; d = dst + 0;       loc = gid; }
    else if (gid <  73728) { src = Wc;  d = dst + 65536;   loc = gid - 8192; }
    else if (gid < 139264) { src = Wb;  d = dst + 589824;  loc = gid - 73728; }
    else if (gid < 155648) { src = Wf;  d = dst + 1114112; loc = gid - 139264; }
    else if (gid < 180224) { src = Wt;  d = dst + 1245184; loc = gid - 155648; }
    else if (gid < 188416) { src = Wg1; d = dst + 1441792; loc = gid - 180224; }
    else                   { src = W1f; d = dst + 1507328; loc = gid - 188416; }
    const float4 v0 = *(const float4*)(src + (size_t)loc * 8);
    const float4 v1 = *(const float4*)(src + (size_t)loc * 8 + 4);
    uint4 o;
    o.x = (u32)f2bf(v0.x) | ((u32)f2bf(v0.y) << 16);
    o.y = (u32)f2bf(v0.z) | ((u32)f2bf(v0.w) << 16);
    o.z = (u32)f2bf(v1.x) | ((u32)f2bf(v1.y) << 16);
    o.w = (u32)f2bf(v1.z) | ((u32)f2bf(v1.w) << 16);
    *(uint4*)(d + (size_t)loc * 8) = o;
}

// ---------- projection GEMM (R6/R10 structure, verified best) ----------
__global__ __launch_bounds__(256)
void gemm_proj(const float* __restrict__ A0, const float* __restrict__ A1,
               const float* __restrict__ A2, const float* __restrict__ A3,
               const u16* __restrict__ Wp0, const u16* __restrict__ Wp1,
               const u16* __restrict__ Wp2, const u16* __restrict__ Wp3,
               const float* __restrict__ b0, const float* __restrict__ b1,
               const float* __restrict__ b2, const float* __restrict__ b3,
               u16* __restrict__ fb)
{
    __shared__ u16 As[2][4096];
    __shared__ u16 Bs[2][16384];
    const int m = blockIdx.y;
    const float* A  = (m == 0) ? A0 : (m == 1) ? A1 : (m == 2) ? A2 : A3;
    const u16* Wp   = (m == 0) ? Wp0 : (m == 1) ? Wp1 : (m == 2) ? Wp2 : Wp3;
    const float* bi = (m == 0) ? b0 : (m == 1) ? b1 : (m == 2) ? b2 : b3;
    const int K     = (m == 0) ? 2048 : (m == 1) ? 2048 : (m == 2) ? 512 : 768;
    const int nt = K >> 6;

    const int t = threadIdx.x;
    const int w = t >> 6, l = t & 63;
    const int bm = blockIdx.x * 64;
    const int arow = t >> 2, akq = t & 3;

    float4 rA[4], rB[4];
    auto loadA = [&](int k0, float4* r) {
        const float* g = A + (size_t)(bm + arow) * K + k0 + akq * 16;
#pragma unroll
        for (int q = 0; q < 4; ++q) r[q] = *(const float4*)(g + q * 4);
    };
    auto writeA = [&](int buf, const float4* r) {
        bf16x8 p0, p1;
        p0[0] = (short)f2bf(r[0].x); p0[1] = (short)f2bf(r[0].y);
        p0[2] = (short)f2bf(r[0].z); p0[3] = (short)f2bf(r[0].w);
        p0[4] = (short)f2bf(r[1].x); p0[5] = (short)f2bf(r[1].y);
        p0[6] = (short)f2bf(r[1].z); p0[7] = (short)f2bf(r[1].w);
        p1[0] = (short)f2bf(r[2].x); p1[1] = (short)f2bf(r[2].y);
        p1[2] = (short)f2bf(r[2].z); p1[3] = (short)f2bf(r[2].w);
        p1[4] = (short)f2bf(r[3].x); p1[5] = (short)f2bf(r[3].y);
        p1[6] = (short)f2bf(r[3].z); p1[7] = (short)f2bf(r[3].w);
        char* abw = (char*)As[buf];
        *(bf16x8*)(abw + arow * 128 + (((akq * 2 + 0) ^ (arow & 7)) << 4)) = p0;
        *(bf16x8*)(abw + arow * 128 + (((akq * 2 + 1) ^ (arow & 7)) << 4)) = p1;
    };
    auto issueB = [&](int k0, int buf) {
#pragma unroll
        for (int it = 0; it < 8; ++it) {
            const int n  = it * 32 + w * 8 + (l >> 3);
            const int ch = (l & 7) ^ (n & 7);
            async_g2l(Wp + (size_t)n * K + k0 + ch * 8, Bs[buf] + it * 2048 + w * 512);
        }
    };

    f32x4 acc[4][4];
    const f32x4 z = {0.f, 0.f, 0.f, 0.f};
#pragma unroll
    for (int i = 0; i < 4; ++i)
#pragma unroll
        for (int j = 0; j < 4; ++j) acc[i][j] = z;

    auto compute = [&](const char* abr, const char* bbr) {
#pragma unroll
        for (int kk = 0; kk < 2; ++kk) {
            bf16x8 af[4], bq[4];
            const int ch = kk * 4 + (l >> 4);
#pragma unroll
            for (int i = 0; i < 4; ++i) {
                const int fr = i * 16 + (l & 15);
                af[i] = *(const bf16x8*)(abr + fr * 128 + ((ch ^ (fr & 7)) << 4));
            }
#pragma unroll
            for (int j = 0; j < 4; ++j) {
                const int n = w * 64 + j * 16 + (l & 15);
                bq[j] = *(const bf16x8*)(bbr + n * 128 + ((ch ^ (n & 7)) << 4));
            }
#pragma unroll
            for (int i = 0; i < 4; ++i)
#pragma unroll
                for (int j = 0; j < 4; ++j)
                    acc[i][j] = __builtin_amdgcn_mfma_f32_16x16x32_bf16(
                        af[i], bq[j], acc[i][j], 0, 0, 0);
        }
    };

    loadA(0, rA);
    writeA(0, rA);
    issueB(0, 0);
    loadA(64, rB);
    issueB(64, 1);
    loadA(128, rA);
    asm volatile("s_waitcnt vmcnt(16) lgkmcnt(0)" ::: "memory");
    __builtin_amdgcn_sched_barrier(0);
    __builtin_amdgcn_s_barrier();

    for (int t0 = 0; t0 < nt; t0 += 2) {
        compute((const char*)As[0], (const char*)Bs[0]);
        writeA(1, rB);
        __builtin_amdgcn_s_barrier();
        if (t0 + 3 < nt) {
            loadA((t0 + 3) * 64, rB);
            issueB((t0 + 2) * 64, 0);
            asm volatile("s_waitcnt vmcnt(12) lgkmcnt(0)" ::: "memory");
        } else if (t0 + 2 < nt) {
            issueB((t0 + 2) * 64, 0);
            asm volatile("s_waitcnt vmcnt(8) lgkmcnt(0)" ::: "memory");
        } else {
            asm volatile("s_waitcnt vmcnt(0) lgkmcnt(0)" ::: "memory");
        }
        __builtin_amdgcn_sched_barrier(0);
        __builtin_amdgcn_s_barrier();

        compute((const char*)As[1], (const char*)Bs[1]);
        if (t0 + 2 < nt) writeA(0, rA);
        __builtin_amdgcn_s_barrier();
        if (t0 + 4 < nt) {
            loadA((t0 + 4) * 64, rA);
            issueB((t0 + 3) * 64, 1);
            asm volatile("s_waitcnt vmcnt(12) lgkmcnt(0)" ::: "memory");
        } else if (t0 + 3 < nt) {
            issueB((t0 + 3) * 64, 1);
            asm volatile("s_waitcnt vmcnt(8) lgkmcnt(0)" ::: "memory");
        } else {
            asm volatile("s_waitcnt vmcnt(0) lgkmcnt(0)" ::: "memory");
        }
        __builtin_amdgcn_sched_barrier(0);
        __builtin_amdgcn_s_barrier();
    }

#pragma unroll
    for (int j = 0; j < 4; ++j) {
        const int col = w * 64 + j * 16 + (l & 15);
        const float bv = bi[col];
#pragma unroll
        for (int i = 0; i < 4; ++i)
#pragma unroll
            for (int r = 0; r < 4; ++r) {
                const int rt = i * 16 + ((l >> 4) << 2) + r;
                fb[((size_t)(bm + rt) * 4 + m) * 256 + col] = f2bf(acc[i][j][r] + bv);
            }
    }
}

// ---------- fused so+gate+combined: BM=32, 48KB LDS (R10, verified) ----------
__global__ __launch_bounds__(256)
void fused_sgc(const u16* __restrict__ fb, const u16* __restrict__ wvo_bf,
               const float* __restrict__ bvo,
               const u16* __restrict__ wg1_bf, const float* __restrict__ bg1,
               const float* __restrict__ wg2, const float* __restrict__ bg2,
               u16* __restrict__ comb)
{
    __shared__ u16 FS[8192];
    __shared__ u16 Bs[2][8192];
    __shared__ float gp[4][32];
    __shared__ float gate_s[32];
    const int t = threadIdx.x, w = t >> 6, l = t & 63;
    const int bm = blockIdx.x * 32;
    char* const fs = (char*)FS;

#pragma unroll
    for (int it = 0; it < 4; ++it) {
        const int r0 = (w * 4 + it) * 2;
        const int row = r0 + (l >> 5);
        const int ch = (l & 31) ^ (row & 7);
        async_g2l(fb + (size_t)(bm + row) * 256 + ch * 8, FS + r0 * 256);
    }
    auto issueB = [&](const u16* Wp, int k0, int buf) {
#pragma unroll
        for (int it = 0; it < 4; ++it) {
            const int n0 = (w * 4 + it) * 16;
            async_g2l(Wp + (size_t)(n0 + (l >> 2)) * 256 + k0 + (l & 3) * 8,
                      Bs[buf] + n0 * 32);
        }
    };
    issueB(wvo_bf, 0, 0);
    __syncthreads();

    const f32x4 z = {0.f, 0.f, 0.f, 0.f};

    // ---- stage 1: so = f @ Wvo^T ----
    f32x4 acc[2][4];
#pragma unroll
    for (int i = 0; i < 2; ++i)
#pragma unroll
        for (int j = 0; j < 4; ++j) acc[i][j] = z;

    for (int ks = 0; ks < 8; ++ks) {
        const int cur = ks & 1;
        if (ks < 7) issueB(wvo_bf, (ks + 1) * 32, cur ^ 1);
        else        issueB(wg1_bf, 0, 0);
        bf16x8 af[2], bq[4];
#pragma unroll
        for (int i = 0; i < 2; ++i) {
            const int row = i * 16 + (l & 15);
            af[i] = *(const bf16x8*)(fs + row * 512 +
                      (((ks * 4 + (l >> 4)) ^ (row & 7)) << 4));
        }
#pragma unroll
        for (int j = 0; j < 4; ++j)
            bq[j] = *(const bf16x8*)((char*)Bs[cur] +
                      (w * 64 + j * 16 + (l & 15)) * 64 + (l >> 4) * 16);
#pragma unroll
        for (int i = 0; i < 2; ++i)
#pragma unroll
            for (int j = 0; j < 4; ++j)
                acc[i][j] = __builtin_amdgcn_mfma_f32_16x16x32_bf16(
                    af[i], bq[j], acc[i][j], 0, 0, 0);
        __syncthreads();
    }

    // write so (bf16, +bvo) back into FS (f is dead)
#pragma unroll
    for (int j = 0; j < 4; ++j) {
        const int col = w * 64 + j * 16 + (l & 15);
        const float bv = bvo[col];
#pragma unroll
        for (int i = 0; i < 2; ++i)
#pragma unroll
            for (int r = 0; r < 4; ++r) {
                const int rt = i * 16 + ((l >> 4) << 2) + r;
                *(u16*)(fs + rt * 512 + (((col >> 3) ^ (rt & 7)) << 4) + (col & 7) * 2)
                    = f2bf(acc[i][j][r] + bv);
            }
    }
    __syncthreads();

    // ---- stage 2: gate GEMM ----
    f32x4 g2[2][4];
#pragma unroll
    for (int i = 0; i < 2; ++i)
#pragma unroll
        for (int j = 0; j < 4; ++j) g2[i][j] = z;

    for (int ks = 0; ks < 8; ++ks) {
        const int cur = ks & 1;
        if (ks < 7) issueB(wg1_bf, (ks + 1) * 32, cur ^ 1);
        bf16x8 af[2], bq[4];
#pragma unroll
        for (int i = 0; i < 2; ++i) {
            const int row = i * 16 + (l & 15);
            af[i] = *(const bf16x8*)(fs + row * 512 +
                      (((ks * 4 + (l >> 4)) ^ (row & 7)) << 4));
        }
#pragma unroll
        for (int j = 0; j < 4; ++j)
            bq[j] = *(const bf16x8*)((char*)Bs[cur] +
                      (w * 64 + j * 16 + (l & 15)) * 64 + (l >> 4) * 16);
#pragma unroll
        for (int i = 0; i < 2; ++i)
#pragma unroll
            for (int j = 0; j < 4; ++j)
                g2[i][j] = __builtin_amdgcn_mfma_f32_16x16x32_bf16(
                    af[i], bq[j], g2[i][j], 0, 0, 0);
        __syncthreads();
    }

    // gate reduce
    {
        float s[2][4];
#pragma unroll
        for (int i = 0; i < 2; ++i)
#pragma unroll
            for (int r = 0; r < 4; ++r) s[i][r] = 0.f;
#pragma unroll
        for (int j = 0; j < 4; ++j) {
            const int col = w * 64 + j * 16 + (l & 15);
            const float bv = bg1[col], wv = wg2[col];
#pragma unroll
            for (int i = 0; i < 2; ++i)
#pragma unroll
                for (int r = 0; r < 4; ++r)
                    s[i][r] += fmaxf(g2[i][j][r] + bv, 0.f) * wv;
        }
#pragma unroll
        for (int off = 1; off < 16; off <<= 1)
#pragma unroll
            for (int i = 0; i < 2; ++i)
#pragma unroll
                for (int r = 0; r < 4; ++r)
                    s[i][r] += __shfl_xor(s[i][r], off);
        if ((l & 15) == 0) {
#pragma unroll
            for (int i = 0; i < 2; ++i)
#pragma unroll
                for (int r = 0; r < 4; ++r)
                    gp[w][i * 16 + ((l >> 4) << 2) + r] = s[i][r];
        }
    }
    __syncthreads();
    if (t < 32) {
        const float g = gp[0][t] + gp[1][t] + gp[2][t] + gp[3][t] + bg2[0];
        gate_s[t] = 1.f / (1.f + expf(-g));
    }
    __syncthreads();

    // ---- stage 3: combined -> global ----
    u32* const comb32 = (u32*)comb;
    const int p2 = t & 127;
    const int gh = t >> 7;
#pragma unroll
    for (int gg = 0; gg < 4; ++gg) {
        const int g = gh * 4 + gg;
        const int d0 = p2 * 2;
        float lo4[4], hi4[4], gv[4];
#pragma unroll
        for (int mm = 0; mm < 4; ++mm) {
            const int row = g * 4 + mm;
            const u32 v = *(const u32*)(fs + row * 512 +
                            (((d0 >> 3) ^ (row & 7)) << 4) + (d0 & 7) * 2);
            lo4[mm] = bf2f_lo(v); hi4[mm] = bf2f_hi(v);
            gv[mm] = gate_s[g * 4 + mm];
        }
        const float cl = 0.25f * (lo4[0] + lo4[1] + lo4[2] + lo4[3]);
        const float ch = 0.25f * (hi4[0] + hi4[1] + hi4[2] + hi4[3]);
#pragma unroll
        for (int mm = 0; mm < 4; ++mm) {
            const float ol = gv[mm] * lo4[mm] + (1.f - gv[mm]) * cl;
            const float oh = gv[mm] * hi4[mm] + (1.f - gv[mm]) * ch;
            comb32[(size_t)(bm + g * 4 + mm) * 128 + p2] =
                (u32)f2bf(ol) | ((u32)f2bf(oh) << 16);
        }
    }
}

// ---------- W1 GEMM + fused BN partial sums (R10, verified) ----------
__global__ __launch_bounds__(256)
void gemm_w1ps(const u16* __restrict__ combp, const u16* __restrict__ w1p,
               const float* __restrict__ b1p, float* __restrict__ h,
               float* __restrict__ psum, float* __restrict__ psq)
{
    __shared__ u16 As[2][1024];
    __shared__ u16 Bs[2][8192];
    const int t = threadIdx.x, w = t >> 6, l = t & 63;
    const int bm = blockIdx.x * 32;
    const int nt = 32;

    auto issueA = [&](int k0, int buf) {
        if (w < 2) {
            const int r0 = w * 16;
            async_g2l(combp + (size_t)(bm + r0 + (l >> 2)) * 1024 + k0 + (l & 3) * 8,
                      As[buf] + r0 * 32);
        }
    };
    auto issueB = [&](int k0, int buf) {
#pragma unroll
        for (int it = 0; it < 4; ++it) {
            const int n0 = (w * 4 + it) * 16;
            async_g2l(w1p + (size_t)(n0 + (l >> 2)) * 1024 + k0 + (l & 3) * 8,
                      Bs[buf] + n0 * 32);
        }
    };

    f32x4 acc[2][4];
    const f32x4 z = {0.f, 0.f, 0.f, 0.f};
#pragma unroll
    for (int i = 0; i < 2; ++i)
#pragma unroll
        for (int j = 0; j < 4; ++j) acc[i][j] = z;

    issueA(0, 0);
    issueB(0, 0);
    __syncthreads();

    for (int t0 = 0; t0 < nt; ++t0) {
        const int cur = t0 & 1;
        if (t0 + 1 < nt) { issueA((t0 + 1) * 32, cur ^ 1); issueB((t0 + 1) * 32, cur ^ 1); }
        const char* ab = (const char*)As[cur];
        const char* bb = (const char*)Bs[cur];
        bf16x8 af[2], bq[4];
#pragma unroll
        for (int i = 0; i < 2; ++i)
            af[i] = *(const bf16x8*)(ab + (i * 16 + (l & 15)) * 64 + (l >> 4) * 16);
#pragma unroll
        for (int j = 0; j < 4; ++j)
            bq[j] = *(const bf16x8*)(bb + (w * 64 + j * 16 + (l & 15)) * 64 + (l >> 4) * 16);
#pragma unroll
        for (int i = 0; i < 2; ++i)
#pragma unroll
            for (int j = 0; j < 4; ++j)
                acc[i][j] = __builtin_amdgcn_mfma_f32_16x16x32_bf16(
                    af[i], bq[j], acc[i][j], 0, 0, 0);
        __syncthreads();
    }

#pragma unroll
    for (int j = 0; j < 4; ++j) {
        const int col = w * 64 + j * 16 + (l & 15);
        const float bv = b1p[col];
        float cs = 0.f, cq = 0.f;
#pragma unroll
        for (int i = 0; i < 2; ++i)
#pragma unroll
            for (int r = 0; r < 4; ++r) {
                const int rt = i * 16 + ((l >> 4) << 2) + r;
                const float v = acc[i][j][r] + bv;
                h[(size_t)(bm + rt) * 256 + col] = v;
                cs += v;
                cq = fmaf(v, v, cq);
            }
        cs += __shfl_xor(cs, 16); cq += __shfl_xor(cq, 16);
        cs += __shfl_xor(cs, 32); cq += __shfl_xor(cq, 32);
        if ((l >> 4) == 0) {
            psum[blockIdx.x * 256 + col] = cs;
            psq[blockIdx.x * 256 + col]  = cq;
        }
    }
}

// ---------- BN finalize: one block per feature column (parallel) ----------
__global__ __launch_bounds__(256)
void bn_fin(const float* __restrict__ psum, const float* __restrict__ psq,
            const float* __restrict__ gamma, const float* __restrict__ beta,
            float* __restrict__ scale, float* __restrict__ shift)
{
    __shared__ float ss[4], qq[4];
    const int d = blockIdx.x;
    const int t = threadIdx.x;
    float s = psum[(size_t)t * 256 + d];
    float q = psq[(size_t)t * 256 + d];
#pragma unroll
    for (int off = 1; off < 64; off <<= 1) {
        s += __shfl_xor(s, off);
        q += __shfl_xor(q, off);
    }
    if ((t & 63) == 0) { ss[t >> 6] = s; qq[t >> 6] = q; }
    __syncthreads();
    if (t == 0) {
        s = ss[0] + ss[1] + ss[2] + ss[3];
        q = qq[0] + qq[1] + qq[2] + qq[3];
        const float mu  = s * (1.f / BSZ);
        const float var = q * (1.f / BSZ) - mu * mu;
        const float inv = rsqrtf(var + BN_EPS);
        const float sc  = gamma[d] * inv;
        scale[d] = sc;
        shift[d] = beta[d] - mu * sc;
    }
}

// ---------- final: out = relu(h*scale+shift) @ W2^T + b2 ----------
__global__ __launch_bounds__(256)
void final_kernel(const float* __restrict__ h, const float* __restrict__ scale,
                  const float* __restrict__ shift, const float* __restrict__ W2,
                  const float* __restrict__ b2, float* __restrict__ out)
{
    __shared__ float W2s[26][260];
    __shared__ float scs[256], shs[256];
    const int t = threadIdx.x;
    for (int u = t; u < 26 * 256; u += 256) {
        const int c = u >> 8, n = u & 255;
        W2s[c][(n >> 6) * 65 + (n & 63)] = W2[u];
    }
    scs[t] = scale[t];
    shs[t] = shift[t];
    __syncthreads();

    const int r = blockIdx.x * 64 + (t >> 2);
    const int p = t & 3;
    float acc[26];
#pragma unroll
    for (int c = 0; c < 26; ++c) acc[c] = 0.f;
    const float* hr = h + (size_t)r * 256 + p * 64;
#pragma unroll
    for (int i4 = 0; i4 < 16; ++i4) {
        const float4 v4 = *(const float4*)(hr + i4 * 4);
#pragma unroll
        for (int q = 0; q < 4; ++q) {
            const int i = i4 * 4 + q;
            const int n = p * 64 + i;
            const float vv = (q == 0) ? v4.x : (q == 1) ? v4.y : (q == 2) ? v4.z : v4.w;
            const float v = fmaxf(fmaf(vv, scs[n], shs[n]), 0.f);
            const int sw = p * 65 + i;
#pragma unroll
            for (int c = 0; c < 26; ++c)
                acc[c] = fmaf(v, W2s[c][sw], acc[c]);
        }
    }
#pragma unroll
    for (int off = 1; off < 4; off <<= 1)
#pragma unroll
        for (int c = 0; c < 26; ++c)
            acc[c] += __shfl_xor(acc[c], off);
    if (p == 0) {
#pragma unroll
        for (int c = 0; c < 26; ++c)
            out[(size_t)r * 26 + c] = acc[c] + b2[c];
    }
}

// ---------- launch ----------
extern "C" void kernel_launch(void* const* d_in, const int* in_sizes, int n_in,
                              void* d_out, int out_size, void* d_ws, size_t ws_size,
                              hipStream_t stream)
{
    const float* x_ctx  = (const float*)d_in[0];
    const float* x_body = (const float*)d_in[1];
    const float* x_face = (const float*)d_in[2];
    const float* x_text = (const float*)d_in[3];
    const float* Wc = (const float*)d_in[4];  const float* bc = (const float*)d_in[5];
    const float* Wb = (const float*)d_in[6];  const float* bb = (const float*)d_in[7];
    const float* Wf = (const float*)d_in[8];  const float* bf = (const float*)d_in[9];
    const float* Wt = (const float*)d_in[10]; const float* bt = (const float*)d_in[11];
    const float* in_w  = (const float*)d_in[12]; const float* in_b  = (const float*)d_in[13];
    const float* out_w = (const float*)d_in[14]; const float* out_b = (const float*)d_in[15];
    const float* Wg1 = (const float*)d_in[16]; const float* bg1 = (const float*)d_in[17];
    const float* Wg2 = (const float*)d_in[18]; const float* bg2 = (const float*)d_in[19];
    const float* W1  = (const float*)d_in[20]; const float* b1  = (const float*)d_in[21];
    const float* gamma = (const float*)d_in[22]; const float* beta = (const float*)d_in[23];
    const float* W2  = (const float*)d_in[24]; const float* b2  = (const float*)d_in[25];

    char* wsb = (char*)d_ws;
    u16*   f_bf  = (u16*)(wsb + 0);                    // 16 MB  [32768][256]
    u16*   comb  = f_bf;                               // overlay: fused_sgc same-row
    float* h     = (float*)(wsb + (16u << 20));        //  8 MB  [8192][256]
    u16*   wpb   = (u16*)(wsb + (32u << 20));          // 3.54 MB packed bf16 weights
    float* wvo   = (float*)(wsb + (36u << 20));        // 256 KB
    float* bvo   = (float*)(wsb + (36u << 20) + 262144);
    float* psum  = (float*)(wsb + (37u << 20));        // 256 KB [256][256]
    float* psq   = (float*)(wsb + (37u << 20) + 262144);
    float* scale = (float*)(wsb + (37u << 20) + 524288);
    float* shift = (float*)(wsb + (37u << 20) + 528384);

    u16* wvo_bf = wpb + 0;
    u16* wc_bf  = wpb + 65536;
    u16* wb_bf  = wpb + 589824;
    u16* wf_bf  = wpb + 1114112;
    u16* wt_bf  = wpb + 1245184;
    u16* wg1_bf = wpb + 1441792;
    u16* w1_bf  = wpb + 1507328;

    wvo_kernel<<<256, 256, 0, stream>>>(in_w, in_b, out_w, out_b, wvo, bvo);
    cvt_weights<<<864, 256, 0, stream>>>(wvo, Wc, Wb, Wf, Wt, Wg1, W1, wpb);

    // modality projections -> f_bf [32768][256] (row = b*4+m)
    gemm_proj<<<dim3(128, 4), 256, 0, stream>>>(x_ctx, x_body, x_face, x_text,
                                                wc_bf, wb_bf, wf_bf, wt_bf,
                                                bc, bb, bf, bt, f_bf);

    // so + gate + combined fused; 1024 blocks
    fused_sgc<<<1024, 256, 0, stream>>>(f_bf, wvo_bf, bvo, wg1_bf, bg1,
                                        Wg2, bg2, comb);

    // h = comb @ W1^T + b1, with fused BN partial sums
    gemm_w1ps<<<256, 256, 0, stream>>>(comb, w1_bf, b1, h, psum, psq);

    bn_fin<<<256, 256, 0, stream>>>(psum, psq, gamma, beta, scale, shift);
    final_kernel<<<128, 256, 0, stream>>>(h, scale, shift, W2, b2, (float*)d_out);
}